// Round 9
// baseline (166.095 us; speedup 1.0000x reference)
//
#include <hip/hip_runtime.h>
#include <stdint.h>

// CrossAttention as 3 GEMM launches + tiny weight-prep.
// out = softmax((hs@Wq)(dhs@Wk)^T / 32) @ (dhs@Wv);  B=4, QL=KL=2048, D=1024.
// R9: killed the big prep pass -- fp32->bf16 cast folded into a merged KV+Q
// GEMM via reg-staged A (fp32 loads one tile ahead, cvt, swizzled ds_write);
// B via global_load_lds. S/PV kernels unchanged from R7 (template ceiling).

typedef __bf16 bf16_t;
typedef __bf16 bf16x8 __attribute__((ext_vector_type(8)));
typedef __bf16 bf16x4 __attribute__((ext_vector_type(4)));
typedef float  f32x4  __attribute__((ext_vector_type(4)));

#define MFMA_BF16(A, B, C) __builtin_amdgcn_mfma_f32_16x16x32_bf16((A), (B), (C), 0, 0, 0)
#define ATTN_SHIFT 16.0f

__device__ __forceinline__ void async_copy16(const void* g, void* l) {
  __builtin_amdgcn_global_load_lds(
      (const __attribute__((address_space(1))) uint32_t*)g,
      (__attribute__((address_space(3))) uint32_t*)l, 16, 0, 0);
}

#define PH_PRE()                                             \
  do {                                                       \
    __builtin_amdgcn_sched_barrier(0);                       \
    __builtin_amdgcn_s_barrier();                            \
    asm volatile("s_waitcnt lgkmcnt(0)" ::: "memory");       \
    __builtin_amdgcn_sched_barrier(0);                       \
    __builtin_amdgcn_s_setprio(1);                           \
  } while (0)
#define PH_POST()                                            \
  do {                                                       \
    __builtin_amdgcn_s_setprio(0);                           \
    __builtin_amdgcn_sched_barrier(0);                       \
    __builtin_amdgcn_s_barrier();                            \
  } while (0)

// ---------------- weight prep: transpose+cast Wq (x1/32), Wkv; zero rowsum ----------------
__global__ void wprep_kernel(const float* __restrict__ Wq, const float* __restrict__ Wkv,
                             bf16_t* __restrict__ WqT, bf16_t* __restrict__ WkvT,
                             float* __restrict__ rowsum) {
  __shared__ float tile[32][33];
  const int bx = blockIdx.x, tid = threadIdx.x;
  if (bx >= 3072) {  // 8 blocks x 256 thr x 4 = 8192 rowsum zeros
    int i0 = (bx - 3072) * 1024 + tid * 4;
#pragma unroll
    for (int j = 0; j < 4; ++j) rowsum[i0 + j] = 0.f;
    return;
  }
  int r0 = (bx / 96) * 32, cb = bx % 96;
  const float* src; bf16_t* dst; int R, C; float scale;
  if (cb < 32) { src = Wq;  dst = WqT;  R = 1024; C = 1024; scale = 0.03125f; }
  else         { src = Wkv; dst = WkvT; R = 1024; C = 2048; scale = 1.0f; cb -= 32; }
  int c0 = cb * 32;
  int tx = tid & 31, ty = tid >> 5;  // 32 x 8
#pragma unroll
  for (int i = 0; i < 4; ++i) {
    int r = ty + i * 8;
    tile[r][tx] = src[(size_t)(r0 + r) * C + c0 + tx] * scale;
  }
  __syncthreads();
#pragma unroll
  for (int i = 0; i < 4; ++i) {
    int c = ty + i * 8;
    dst[(size_t)(c0 + c) * R + r0 + tx] = (bf16_t)tile[tx][c];
  }
}

// ---------------- merged KV+Q GEMM with fused fp32->bf16 A-cast ----------------
// Grid 1536 (T1-swizzled): blocks [0,1024) KV = dhs@Wkv (K->Kb, V->VT);
// blocks [1024,1536) Q = hs@(Wq/32) -> Qb.  BM=BN=128, BK=64, 4 waves (2x2),
// LDS 64KB (A bf16 2x16KB + B 2x16KB) -> 2 blocks/CU.
// A: fp32 reg-staged (issue t+3's loads in slot t; vmcnt(0) at slot start is
// free -- loads have a full tile in flight), cvt, T2-swizzled ds_write_b128.
// B: global_load_lds with pre-swizzled source. Full drain per tile => no
// counted-vmcnt hazards. K=1024, NT=16.
__global__ __launch_bounds__(256, 2) void kvq_kernel(
    const float* __restrict__ dhs, const float* __restrict__ hs,
    const bf16_t* __restrict__ WkvT, const bf16_t* __restrict__ WqT,
    bf16_t* __restrict__ Kb, bf16_t* __restrict__ VTb, bf16_t* __restrict__ Qb) {
  __shared__ char smem[65536];

  const int bx0 = blockIdx.x;
  const int q8 = gridDim.x >> 3;                 // 192
  const int swz = (bx0 & 7) * q8 + (bx0 >> 3);   // bijective XCD chunking
  const float* Afp; const bf16_t* Bt; int rr, nb; bool isKV;
  if (swz < 1024) { isKV = true;  Afp = dhs; Bt = WkvT; rr = swz;        nb = 16; }
  else            { isKV = false; Afp = hs;  Bt = WqT;  rr = swz - 1024; nb = 8;  }
  const int m0 = (rr / nb) << 7;
  const int n0 = (rr % nb) << 7;

  const int tid = threadIdx.x, w = tid >> 6, l = tid & 63;
  const int l15 = l & 15, l4 = l >> 4;
  const int wr = w >> 1, wc = w & 1;             // 2x2 wave grid, 64x64 tiles
  const int lrow = l >> 3;                       // 0..7
  const int gcol = ((l & 7) ^ lrow) << 3;        // pre-swizzled granule (B path)

  const float*  PAf = Afp + (size_t)(m0 + 8 * w + lrow) * 1024 + (l & 7) * 8;
  const bf16_t* PB  = Bt  + (size_t)(n0 + 8 * w + lrow) * 1024 + gcol;

  const int sw16 = (l15 & 7) << 4;
  const int aoff0 = (wr * 64 + l15) * 128;
  const int boff0 = (wc * 64 + l15) * 128;

  f32x4 acc[4][4] = {};
  bf16x8 afA[4], bfA[4], afB[4], bfB[4];
  float4 fa0[8], fa1[8];

  auto issueA = [&](int t, float4 (&f)[8]) {
#pragma unroll
    for (int h = 0; h < 4; ++h) {
      const float* s = PAf + (size_t)(h * 32) * 1024 + (t << 6);
      f[2 * h]     = *(const float4*)(s);
      f[2 * h + 1] = *(const float4*)(s + 4);
    }
  };
  auto writeA = [&](int t, float4 (&f)[8]) {
#pragma unroll
    for (int h = 0; h < 4; ++h) {
      bf16x8 o;
      o[0] = (bf16_t)f[2 * h].x;     o[1] = (bf16_t)f[2 * h].y;
      o[2] = (bf16_t)f[2 * h].z;     o[3] = (bf16_t)f[2 * h].w;
      o[4] = (bf16_t)f[2 * h + 1].x; o[5] = (bf16_t)f[2 * h + 1].y;
      o[6] = (bf16_t)f[2 * h + 1].z; o[7] = (bf16_t)f[2 * h + 1].w;
      *(bf16x8*)(smem + (t & 1) * 16384 +
                 (h * 32 + 8 * w + lrow) * 128 + (((l & 7) ^ lrow) << 4)) = o;
    }
  };
  auto stageB = [&](int t) {
#pragma unroll
    for (int h = 0; h < 4; ++h)
      async_copy16(PB + (size_t)(h * 32) * 1024 + (t << 6),
                   smem + 32768 + (t & 1) * 16384 + h * 4096 + w * 1024);
  };
  auto rdA = [&](bf16x8* dst, const char* base, int kh) {
#pragma unroll
    for (int rf = 0; rf < 4; ++rf)
      dst[rf] = *(const bf16x8*)(base + aoff0 + rf * 2048 + (((kh * 4 + l4) << 4) ^ sw16));
  };
  auto rdB = [&](bf16x8* dst, const char* base, int kh) {
#pragma unroll
    for (int cf = 0; cf < 4; ++cf)
      dst[cf] = *(const bf16x8*)(base + boff0 + cf * 2048 + (((kh * 4 + l4) << 4) ^ sw16));
  };
  auto mfma_half = [&](const bf16x8* afx, const bf16x8* bfx) {
#pragma unroll
    for (int rf = 0; rf < 4; ++rf)
#pragma unroll
      for (int cf = 0; cf < 4; ++cf)
        acc[rf][cf] = MFMA_BF16(afx[rf], bfx[cf], acc[rf][cf]);
  };

  // ---- prologue: A(0),A(1) via regs; B(0),B(1) via DMA; A(2) in flight ----
  issueA(0, fa0); issueA(1, fa1);
  __builtin_amdgcn_sched_barrier(0);
  asm volatile("s_waitcnt vmcnt(0)" ::: "memory");
  writeA(0, fa0); writeA(1, fa1);
  __builtin_amdgcn_sched_barrier(0);
  stageB(0); stageB(1);
  issueA(2, fa0);
  __builtin_amdgcn_sched_barrier(0);
  asm volatile("s_waitcnt vmcnt(8)" ::: "memory");   // B(0),B(1) done; A(2) in flight
  asm volatile("s_waitcnt lgkmcnt(0)" ::: "memory"); // A writes drained
  __builtin_amdgcn_s_barrier();
  __builtin_amdgcn_sched_barrier(0);
  rdA(afA, smem, 0);
  rdB(bfA, smem + 32768, 0);

  auto body = [&](int t, float4 (&cur)[8], float4 (&nxt)[8]) {
    const char* Ac = smem + (t & 1) * 16384;
    const char* Bc = smem + 32768 + (t & 1) * 16384;
    const char* An = smem + ((t + 1) & 1) * 16384;
    const char* Bn = smem + 32768 + ((t + 1) & 1) * 16384;
    // half 0: read kh1 frags (buf p); MFMA kh0 under them
    rdA(afB, Ac, 1);
    rdB(bfB, Bc, 1);
    __builtin_amdgcn_sched_barrier(0);
    __builtin_amdgcn_s_setprio(1);
    mfma_half(afA, bfA);
    __builtin_amdgcn_s_setprio(0);
    __builtin_amdgcn_sched_barrier(0);
    asm volatile("s_waitcnt lgkmcnt(0)" ::: "memory");  // buf p read-dead
    __builtin_amdgcn_s_barrier();
    __builtin_amdgcn_sched_barrier(0);
    // slot: drain (free: loads issued a full tile ago); write A(t+2);
    // DMA B(t+2); issue A(t+3) fp32 loads
    asm volatile("s_waitcnt vmcnt(0)" ::: "memory");
    if (t + 2 < 16) { writeA(t + 2, cur); stageB(t + 2); }
    __builtin_amdgcn_sched_barrier(0);
    if (t + 3 < 16) issueA(t + 3, nxt);
    __builtin_amdgcn_sched_barrier(0);
    __builtin_amdgcn_s_barrier();
    __builtin_amdgcn_sched_barrier(0);
    // half 1: read kh0 frags of t+1 (buf p^1); MFMA kh1 under them
    if (t + 1 < 16) {
      rdA(afA, An, 0);
      rdB(bfA, Bn, 0);
    }
    __builtin_amdgcn_sched_barrier(0);
    __builtin_amdgcn_s_setprio(1);
    mfma_half(afB, bfB);
    __builtin_amdgcn_s_setprio(0);
    __builtin_amdgcn_sched_barrier(0);
  };

#pragma unroll 1
  for (int t = 0; t < 16; t += 2) {
    body(t, fa0, fa1);
    body(t + 1, fa1, fa0);
  }

  // ---- epilogue ----
  if (isKV) {
    if (n0 < 1024) {
#pragma unroll
      for (int rf = 0; rf < 4; ++rf)
#pragma unroll
        for (int cf = 0; cf < 4; ++cf) {
          int grow = m0 + wr * 64 + rf * 16 + l4 * 4;
          int gc = n0 + wc * 64 + cf * 16 + l15;
#pragma unroll
          for (int r = 0; r < 4; ++r)
            Kb[(size_t)(grow + r) * 1024 + gc] = (bf16_t)acc[rf][cf][r];
        }
    } else {
#pragma unroll
      for (int rf = 0; rf < 4; ++rf)
#pragma unroll
        for (int cf = 0; cf < 4; ++cf) {
          int grow0 = m0 + wr * 64 + rf * 16 + l4 * 4;
          int b = grow0 >> 11, kl = grow0 & 2047;
          int d = (n0 - 1024) + wc * 64 + cf * 16 + l15;
          bf16x4 v;
#pragma unroll
          for (int r = 0; r < 4; ++r) v[r] = (bf16_t)acc[rf][cf][r];
          *(bf16x4*)(VTb + (size_t)b * (1024 * 2048) + (size_t)d * 2048 + kl) = v;
        }
    }
  } else {
#pragma unroll
    for (int rf = 0; rf < 4; ++rf)
#pragma unroll
      for (int cf = 0; cf < 4; ++cf) {
        int grow = m0 + wr * 64 + rf * 16 + l4 * 4;
        int gc = n0 + wc * 64 + cf * 16 + l15;
#pragma unroll
        for (int r = 0; r < 4; ++r)
          Qb[(size_t)(grow + r) * 1024 + gc] = (bf16_t)acc[rf][cf][r];
      }
  }
}

// ---------------- 2-phase GEMM (R7, unchanged): C[M,N] = A[M,K] @ Bt[N,K]^T ----------------
template <int BN, int EPI>
__global__ __launch_bounds__(512, 2) void gemm8(
    const bf16_t* __restrict__ A, int lda, size_t sA,
    const bf16_t* __restrict__ Bt, int ldb, size_t sB,
    void* __restrict__ Cv, int ldc, size_t sC,
    void* __restrict__ Cv2, int nb, int bpb, int K, float* __restrict__ rowsum) {
  constexpr int ABYTES = 256 * 64 * 2;
  constexpr int BBYTES = BN * 64 * 2;
  constexpr int WC   = (BN == 256) ? 4 : 2;
  constexpr int MW   = (BN == 256) ? 128 : 64;
  constexpr int NW   = BN / WC;
  constexpr int NRF  = MW / 16;
  constexpr int NCF2 = NW / 16;
  __shared__ char smem[2 * ABYTES + 2 * BBYTES];

  const int bx0 = blockIdx.x;
  const int q8 = gridDim.x >> 3;
  const int swz = (bx0 & 7) * q8 + (bx0 >> 3);
  const int bz = swz / bpb;
  const int rr = swz % bpb;
  const int m0 = (rr / nb) << 8;
  const int n0 = (rr % nb) * BN;

  const bf16_t* Ab = A + (size_t)bz * sA;
  const bf16_t* Bb = Bt + (size_t)bz * sB;
  const int tid = threadIdx.x, w = tid >> 6, l = tid & 63;
  const int l15 = l & 15, l4 = l >> 4;
  const int wc = w & (WC - 1), wr = w / WC;
  const int NT = K >> 6;

  const int lrow = l >> 3;
  const int gcol = ((l & 7) ^ lrow) << 3;
  const bf16_t* PA = Ab + (size_t)(m0 + 8 * w + lrow) * lda + gcol;
  const bf16_t* PB = Bb + (size_t)(n0 + 8 * w + lrow) * ldb + gcol;

  const int sw16 = (l15 & 7) << 4;
  const int aoff0 = (wr * MW + l15) * 128;
  const int boff0 = (wc * NW + l15) * 128;

  f32x4 acc[NRF][NCF2] = {};
  bf16x8 afA[NRF], bfA[NCF2], afB[NRF], bfB[NCF2];

  auto stageA = [&](int t, int h) {
    const bf16_t* s = PA + (size_t)(h * 128) * lda + (t << 6);
    char* d = smem + (t & 1) * ABYTES + h * 16384 + w * 1024;
    async_copy16(s, d);
    async_copy16(s + (size_t)64 * lda, d + 8192);
  };
  auto stageB = [&](int t, int h) {
    const bf16_t* s = PB + (size_t)(h * (BN / 2)) * ldb + (t << 6);
    char* d = smem + 2 * ABYTES + (t & 1) * BBYTES + h * (BBYTES / 2) + w * 1024;
    async_copy16(s, d);
    if constexpr (BN == 256) async_copy16(s + (size_t)64 * ldb, d + 8192);
  };
  auto stageT = [&](int t) {
    if (t >= NT) return;
    stageA(t, 0); stageA(t, 1); stageB(t, 0); stageB(t, 1);
  };
  auto rdA = [&](bf16x8* dst, const char* base, int kh) {
#pragma unroll
    for (int rf = 0; rf < NRF; ++rf)
      dst[rf] = *(const bf16x8*)(base + aoff0 + rf * 2048 + (((kh * 4 + l4) << 4) ^ sw16));
  };
  auto rdB = [&](bf16x8* dst, const char* base, int kh) {
#pragma unroll
    for (int cf = 0; cf < NCF2; ++cf)
      dst[cf] = *(const bf16x8*)(base + boff0 + cf * 2048 + (((kh * 4 + l4) << 4) ^ sw16));
  };
  auto mfma_half = [&](const bf16x8* afx, const bf16x8* bfx) {
#pragma unroll
    for (int rf = 0; rf < NRF; ++rf)
#pragma unroll
      for (int cf = 0; cf < NCF2; ++cf)
        acc[rf][cf] = MFMA_BF16(afx[rf], bfx[cf], acc[rf][cf]);
  };

  stageT(0);
  __builtin_amdgcn_sched_barrier(0);
  stageT(1);
  __builtin_amdgcn_sched_barrier(0);
  if constexpr (BN == 256) asm volatile("s_waitcnt vmcnt(8)" ::: "memory");
  else                     asm volatile("s_waitcnt vmcnt(6)" ::: "memory");
  __builtin_amdgcn_s_barrier();
  __builtin_amdgcn_sched_barrier(0);
  rdA(afA, smem, 0);
  rdB(bfA, smem + 2 * ABYTES, 0);

  for (int t = 0; t < NT; ++t) {
    const char* Ac = smem + (t & 1) * ABYTES;
    const char* Bc = smem + 2 * ABYTES + (t & 1) * BBYTES;
    const char* An = smem + ((t + 1) & 1) * ABYTES;
    const char* Bn = smem + 2 * ABYTES + ((t + 1) & 1) * BBYTES;
    rdA(afB, Ac, 1);
    rdB(bfB, Bc, 1);
    __builtin_amdgcn_sched_barrier(0);
    __builtin_amdgcn_s_setprio(1);
    mfma_half(afA, bfA);
    __builtin_amdgcn_s_setprio(0);
    __builtin_amdgcn_sched_barrier(0);
    asm volatile("s_waitcnt lgkmcnt(0)" ::: "memory");
    __builtin_amdgcn_s_barrier();
    __builtin_amdgcn_sched_barrier(0);
    stageT(t + 2);
    __builtin_amdgcn_sched_barrier(0);
    if (t < NT - 2) {
      if constexpr (BN == 256) asm volatile("s_waitcnt vmcnt(8)" ::: "memory");
      else                     asm volatile("s_waitcnt vmcnt(6)" ::: "memory");
    } else {
      asm volatile("s_waitcnt vmcnt(0)" ::: "memory");
    }
    __builtin_amdgcn_s_barrier();
    __builtin_amdgcn_sched_barrier(0);
    if (t + 1 < NT) {
      rdA(afA, An, 0);
      rdB(bfA, Bn, 0);
    }
    __builtin_amdgcn_sched_barrier(0);
    __builtin_amdgcn_s_setprio(1);
    mfma_half(afB, bfB);
    __builtin_amdgcn_s_setprio(0);
    __builtin_amdgcn_sched_barrier(0);
  }

  __syncthreads();

  if constexpr (EPI == 1) {
    bf16_t* Cb = (bf16_t*)Cv + (size_t)bz * sC;
    float* rsh = (float*)smem;
    if (tid < 256) rsh[tid] = 0.f;
    __syncthreads();
#pragma unroll
    for (int rf = 0; rf < NRF; ++rf)
#pragma unroll
      for (int r = 0; r < 4; ++r) {
        int lr = wr * MW + rf * 16 + l4 * 4 + r;
        float s = 0.f;
#pragma unroll
        for (int cf = 0; cf < NCF2; ++cf) {
          float p = __expf(acc[rf][cf][r] - ATTN_SHIFT);
          bf16_t pb = (bf16_t)p;
          Cb[(size_t)(m0 + lr) * ldc + n0 + wc * NW + cf * 16 + l15] = pb;
          s += (float)pb;
        }
        s += __shfl_xor(s, 1); s += __shfl_xor(s, 2);
        s += __shfl_xor(s, 4); s += __shfl_xor(s, 8);
        if (l15 == 0) atomicAdd(&rsh[lr], s);
      }
    __syncthreads();
    if (tid < 256) atomicAdd(&rowsum[(size_t)bz * 2048 + m0 + tid], rsh[tid]);
  } else if constexpr (EPI == 2) {
    float* rsh = (float*)smem;
    if (tid < 256) rsh[tid] = rowsum[(size_t)bz * 2048 + m0 + tid];
    __syncthreads();
    float* Cb = (float*)Cv + (size_t)bz * sC;
#pragma unroll
    for (int rf = 0; rf < NRF; ++rf)
#pragma unroll
      for (int r = 0; r < 4; ++r) {
        float inv = 1.0f / rsh[wr * MW + rf * 16 + l4 * 4 + r];
        int grow = m0 + wr * MW + rf * 16 + l4 * 4 + r;
#pragma unroll
        for (int cf = 0; cf < NCF2; ++cf)
          Cb[(size_t)grow * ldc + n0 + wc * NW + cf * 16 + l15] = acc[rf][cf][r] * inv;
      }
  }
}

// ---------------- launcher ----------------
extern "C" void kernel_launch(void* const* d_in, const int* in_sizes, int n_in,
                              void* d_out, int out_size, void* d_ws, size_t ws_size,
                              hipStream_t stream) {
  const float* hs  = (const float*)d_in[0];   // [4,2048,1024]
  const float* dhs = (const float*)d_in[1];   // [4,2048,1024]
  const float* Wq  = (const float*)d_in[2];   // [1024,1024]
  const float* Wkv = (const float*)d_in[3];   // [1024,2048]
  float* out = (float*)d_out;

  const size_t M1 = 1024 * 1024;
  bf16_t* WqT  = (bf16_t*)d_ws;           // 1M elems (Wq^T / 32)
  bf16_t* WkvT = WqT + M1;                // 2M elems
  bf16_t* P    = WkvT + 2 * M1;           // 16M elems  P [4][2048][2048]
  bf16_t* Kb   = P + 16 * M1;             // 8M elems   K [4*2048][1024]
  bf16_t* VTb  = Kb + 8 * M1;             // 8M elems   VT [4][1024][2048]
  bf16_t* Qb   = VTb + 8 * M1;            // 8M elems   Q [4*2048][1024] (pre-scaled)
  float* rowsum = (float*)(Qb + 8 * M1);  // 8192 fp32

  wprep_kernel<<<3080, 256, 0, stream>>>(Wq, Wkv, WqT, WkvT, rowsum);

  // merged KV + Q projections with fused fp32->bf16 cast
  kvq_kernel<<<1536, 256, 0, stream>>>(dhs, hs, WkvT, WqT, Kb, VTb, Qb);

  // P = exp(Q K^T - 16) + rowsums : per batch M=N=2048, K=1024
  gemm8<256, 1><<<256, 512, 0, stream>>>(
      Qb, 1024, (size_t)2048 * 1024, Kb, 1024, (size_t)2048 * 1024,
      P, 2048, (size_t)2048 * 2048, nullptr, 8, 64, 1024, rowsum);
  // out = (P @ V) / rowsum : per batch M=2048, N=1024, K=2048
  gemm8<128, 2><<<256, 512, 0, stream>>>(
      P, 2048, (size_t)2048 * 2048, VTb, 2048, (size_t)1024 * 2048,
      out, 1024, (size_t)2048 * 1024, nullptr, 8, 64, 2048, rowsum);
}